// Round 14
// baseline (921.815 us; speedup 1.0000x reference)
//
#include <hip/hip_runtime.h>

#define SCALE_EPS 1e-5f

typedef int v4i __attribute__((ext_vector_type(4)));
typedef int v16i __attribute__((ext_vector_type(16)));

static __device__ __forceinline__ void gll16(const void* g, void* l) {
  __builtin_amdgcn_global_load_lds(
      (const __attribute__((address_space(1))) unsigned int*)g,
      (__attribute__((address_space(3))) unsigned int*)l,
      16, 0, 0);
}

// Nibble-pair packed operand format (both A and B), biased u = q+8:
//   packed byte e of a 32x32 k-pair fragment: u[k] | u[k+32]<<4
//   fragment lane l = kh*32 + (row_or_col % 32); ds_read_b128 yields BOTH
//   ks=0 (lo nibbles) and ks=1 (hi nibbles) v4i MFMA operands.
// A tile (256 rows x 64 k, packed 8 KiB) at xq + (mt*64+kc)*8192
// B tile (256 cols x 64 k, packed 8 KiB) at wq + (nt*64+kc)*8192
// Bias removal: C = raw - 8*(sa_signed[t] + swU_biased[o])  (exact).

// ---------------------------------------------------------------------------
// Weight unpack: packed int32 [4096][2048] -> biased nibble-pair tiles.
// ---------------------------------------------------------------------------
__global__ __launch_bounds__(256) void unpack_w(const int* __restrict__ wp,
                                                char* __restrict__ wq) {
  const int kc = blockIdx.x;   // 0..63
  const int nt2 = blockIdx.y;  // 0..15 (256-col tiles)
  const int tid = threadIdx.x;
  char* tile = wq + ((size_t)nt2 * 64 + kc) * 8192;
#pragma unroll
  for (int it = 0; it < 8; ++it) {
    int idx = it * 256 + tid;      // 0..2047
    int c = idx >> 3;              // col in tile 0..255
    int rem = idx & 7;
    int kh = rem >> 2, q = rem & 3;
    const int* src = wp + (size_t)(nt2 * 256 + c) * 2048 + kc * 32 + kh * 8 + q * 2;
    int i0 = src[0], i1 = src[1], j0 = src[16], j1 = src[17];
    unsigned dw = ((unsigned)i0 & 15) | (((unsigned)j0 & 15) << 4) |
                  ((((unsigned)i0 >> 4) & 15) << 8) | ((((unsigned)j0 >> 4) & 15) << 12) |
                  (((unsigned)i1 & 15) << 16) | (((unsigned)j1 & 15) << 20) |
                  ((((unsigned)i1 >> 4) & 15) << 24) | ((((unsigned)j1 >> 4) & 15) << 28);
    dw ^= 0x88888888u;  // raw nibble v -> v^8 = q+8 (biased)
    *(unsigned*)(tile + (c >> 5) * 1024 + (kh * 32 + (c & 31)) * 16 + q * 4) = dw;
  }
}

// ---------------------------------------------------------------------------
// Per-out-feature BIASED nibble sum: swU[o] = sum_k (q_w + 8).
// ---------------------------------------------------------------------------
__global__ __launch_bounds__(256) void sum_w(const int* __restrict__ wp,
                                             int* __restrict__ sw) {
  __shared__ int ls[4];
  const int row = blockIdx.x;
  const int tid = threadIdx.x;
  const v4i* src = (const v4i*)(wp + (size_t)row * 2048 + tid * 8);
  v4i m0 = src[0], m1 = src[1];
  int s = 0;
#pragma unroll
  for (int j = 0; j < 4; ++j) {
    int a = (j == 0) ? m0.x : (j == 1) ? m0.y : (j == 2) ? m0.z : m0.w;
    int b = (j == 0) ? m1.x : (j == 1) ? m1.y : (j == 2) ? m1.z : m1.w;
    s += ((a & 15) ^ 8) + (((a >> 4) & 15) ^ 8) + ((b & 15) ^ 8) + (((b >> 4) & 15) ^ 8);
  }
#pragma unroll
  for (int d = 1; d < 64; d <<= 1) s += __shfl_xor(s, d, 64);
  if ((tid & 63) == 0) ls[tid >> 6] = s;
  __syncthreads();
  if (tid == 0) sw[row] = ls[0] + ls[1] + ls[2] + ls[3];
}

// ---------------------------------------------------------------------------
// Activation quant: per-row absmax scale, q = clip(rint(x/scale),-8,7),
// nibble-pair packed tiles (u = q+8) + per-token SIGNED sum sa[t].
// ---------------------------------------------------------------------------
__global__ __launch_bounds__(256) void quant_x(const float* __restrict__ x,
                                               char* __restrict__ xq,
                                               float* __restrict__ xs,
                                               int* __restrict__ sa) {
  __shared__ float lmax[4][4];
  __shared__ int lsum[4][4];
  const int tid = threadIdx.x;
  const int w = tid >> 6;        // wave -> 16 kc chunk
  const int l = tid & 63;
  const int t0 = blockIdx.x * 4;
  const int row = l >> 4;
  const int t = t0 + row;
  const int sub = l & 15;
  const int kcl = sub >> 3;      // which of 2 kc per s
  const int kh = (sub >> 2) & 1;
  const int j = sub & 3;

  float4 va[8], vb[8];
  float m = 0.0f;
#pragma unroll
  for (int s = 0; s < 8; ++s) {
    int kc = w * 16 + s * 2 + kcl;
    const float* p = x + (size_t)t * 4096 + kc * 64 + kh * 16 + j * 4;
    va[s] = *(const float4*)(p);
    vb[s] = *(const float4*)(p + 32);
    m = fmaxf(m, fmaxf(fmaxf(fabsf(va[s].x), fabsf(va[s].y)),
                       fmaxf(fabsf(va[s].z), fabsf(va[s].w))));
    m = fmaxf(m, fmaxf(fmaxf(fabsf(vb[s].x), fabsf(vb[s].y)),
                       fmaxf(fabsf(vb[s].z), fabsf(vb[s].w))));
  }
#pragma unroll
  for (int d = 1; d < 16; d <<= 1) m = fmaxf(m, __shfl_xor(m, d, 64));
  if (sub == 0) lmax[w][row] = m;
  __syncthreads();
  float rm = fmaxf(fmaxf(lmax[0][row], lmax[1][row]),
                   fmaxf(lmax[2][row], lmax[3][row]));
  float scale = fmaxf(rm / 7.0f, SCALE_EPS);
  if (w == 0 && sub == 0) xs[t] = scale;

  char* dst0 = xq + (size_t)(t >> 8) * 524288 + ((t & 255) >> 5) * 1024 +
               (kh * 32 + (t & 31)) * 16 + j * 4;

  int isum = 0;
#pragma unroll
  for (int s = 0; s < 8; ++s) {
    int kc = w * 16 + s * 2 + kcl;
    int q0 = (int)fminf(fmaxf(rintf(va[s].x / scale), -8.0f), 7.0f);
    int q1 = (int)fminf(fmaxf(rintf(va[s].y / scale), -8.0f), 7.0f);
    int q2 = (int)fminf(fmaxf(rintf(va[s].z / scale), -8.0f), 7.0f);
    int q3 = (int)fminf(fmaxf(rintf(va[s].w / scale), -8.0f), 7.0f);
    int q4 = (int)fminf(fmaxf(rintf(vb[s].x / scale), -8.0f), 7.0f);
    int q5 = (int)fminf(fmaxf(rintf(vb[s].y / scale), -8.0f), 7.0f);
    int q6 = (int)fminf(fmaxf(rintf(vb[s].z / scale), -8.0f), 7.0f);
    int q7 = (int)fminf(fmaxf(rintf(vb[s].w / scale), -8.0f), 7.0f);
    isum += q0 + q1 + q2 + q3 + q4 + q5 + q6 + q7;
    unsigned dw = (unsigned)((q0 + 8) | ((q4 + 8) << 4)) |
                  ((unsigned)((q1 + 8) | ((q5 + 8) << 4)) << 8) |
                  ((unsigned)((q2 + 8) | ((q6 + 8) << 4)) << 16) |
                  ((unsigned)((q3 + 8) | ((q7 + 8) << 4)) << 24);
    *(unsigned*)(dst0 + (size_t)kc * 8192) = dw;
  }
#pragma unroll
  for (int dd = 1; dd < 16; dd <<= 1) isum += __shfl_xor(isum, dd, 64);
  if (sub == 0) lsum[w][row] = isum;
  __syncthreads();
  if (w == 0 && sub == 0)
    sa[t] = lsum[0][row] + lsum[1][row] + lsum[2][row] + lsum[3][row];
}

// ---------------------------------------------------------------------------
// Packed-nibble GEMM, 256x256 tile, 8 waves (2Mx4N), BK=64, mfma 32x32x32 i8.
// R13 = R12 with the stage-stride bug fixed: tiles are 8192 B apart (256-row
// packed tiles), R12 advanced aS/bS by 4096 (stale 128-tile stride) -> staged
// garbage K-data (absmax 66). All K-loop addressing is literal offsets off
// hoisted pointers (asl/bsl/dal/dbl[4]); stage pointers advance +8192/tile.
// Schedule = R8's proven skeleton: mid-tile counted vmcnt(2)+barrier,
// packed-pair rotation, splat-vector unpack, setprio.
// Epilogue: C = raw - 8*(sa + swU)  (exact).
// ---------------------------------------------------------------------------
__global__ __launch_bounds__(512, 2) void gemm_i8(const char* __restrict__ xq,
                                                  const char* __restrict__ wq,
                                                  const float* __restrict__ xs,
                                                  const int* __restrict__ sa,
                                                  const int* __restrict__ sw,
                                                  const float* __restrict__ wsc,
                                                  float* __restrict__ out) {
  __shared__ char lds[4][16384];
  const int tid = threadIdx.x;
  const int wid = tid >> 6;
  const int lane = tid & 63;
  const int wm = wid >> 2;         // 0..1 : M half (128 rows)
  const int wn = wid & 3;          // 0..3 : N quarter (64 cols)

  const int bid = blockIdx.x;
  const int wg = (bid & 7) * 64 + (bid >> 3);
  const int by = wg >> 4;          // 0..31
  const int bx = wg & 15;          // 0..15

  const int toff = tid * 16;       // 0..8191
  const int laoff = lane * 16;

  // hoisted pointers (computed once; all K-loop addressing is literal offsets)
  const char* asl[4];              // per-slot A read base
  const char* bsl[4];              // per-slot B read base
  char* dal[4];                    // per-slot A DMA dest
  char* dbl[4];                    // per-slot B DMA dest
#pragma unroll
  for (int s = 0; s < 4; ++s) {
    asl[s] = lds[s] + wm * 4096 + laoff;
    bsl[s] = lds[s] + 8192 + wn * 2048 + laoff;
    dal[s] = lds[s] + toff;
    dbl[s] = lds[s] + 8192 + toff;
  }
  const char* aS = xq + (size_t)by * 524288 + toff;  // stage src, tile 0
  const char* bS = wq + (size_t)bx * 524288 + toff;

  v16i acc[4][2] = {};             // acc[rb][nf]
  v4i pA0, pA1, pA2, pA3, pB0, pB1;                  // packed (next tile)
  v4i a00, a01, a10, a11, a20, a21, a30, a31;        // unpacked A [rb][ks]
  v4i b00, b01, b10, b11;                            // unpacked B [nf][ks]
  const v4i M4 = (v4i)(0x0f0f0f0f);

#define UNPK(d0, d1, p)                            \
  do {                                             \
    d0 = (p) & M4;                                 \
    d1 = ((p) >> 4) & M4;                          \
  } while (0)

  // 4 mfma: rows {rb, rb+1} x col-frags {0,1}
#define CL(rb, xx, yy, bA, bB)                                                 \
  do {                                                                         \
    __builtin_amdgcn_s_setprio(1);                                             \
    acc[rb][0] = __builtin_amdgcn_mfma_i32_32x32x32_i8(xx, bA, acc[rb][0], 0, 0, 0);   \
    acc[rb][1] = __builtin_amdgcn_mfma_i32_32x32x32_i8(xx, bB, acc[rb][1], 0, 0, 0);   \
    acc[rb + 1][0] = __builtin_amdgcn_mfma_i32_32x32x32_i8(yy, bA, acc[rb + 1][0], 0, 0, 0); \
    acc[rb + 1][1] = __builtin_amdgcn_mfma_i32_32x32x32_i8(yy, bB, acc[rb + 1][1], 0, 0, 0); \
    __builtin_amdgcn_s_setprio(0);                                             \
  } while (0)

  // One K-tile. s = kt&3 (current slot), sn = (kt+1)&3, ss = (kt+3)&3 —
  // all literals after unrolling. Stage advances aS/bS by one tile (8192 B).
#define TILE(s, sn, ss, do_stage, do_next, vm)                               \
  do {                                                                       \
    /* first half: unpack rb2,rb3 (held from prev tile); ks0 MFMAs */        \
    UNPK(a20, a21, pA2);                                                     \
    UNPK(a30, a31, pA3);                                                     \
    CL(0, a00, a10, b00, b10);                                               \
    CL(2, a20, a30, b00, b10);                                               \
    /* mid-tile: certify slot sn's DMA (counted), sync */                    \
    if ((vm) == 2) asm volatile("s_waitcnt vmcnt(2)" ::: "memory");          \
    else if ((vm) == 0) asm volatile("s_waitcnt vmcnt(0)" ::: "memory");     \
    __builtin_amdgcn_s_barrier();                                            \
    __builtin_amdgcn_sched_barrier(0);                                       \
    /* second half: stage slot ss; read slot sn packed; ks1 MFMAs; unpack */ \
    if (do_stage) {                                                          \
      gll16(aS, dal[ss]);                                                    \
      gll16(bS, dbl[ss]);                                                    \
      aS += 8192; bS += 8192;                                                \
    }                                                                        \
    if (do_next) {                                                           \
      pA0 = *(const v4i*)(asl[sn]);                                          \
      pA1 = *(const v4i*)(asl[sn] + 1024);                                   \
      pB0 = *(const v4i*)(bsl[sn]);                                          \
      pB1 = *(const v4i*)(bsl[sn] + 1024);                                   \
    }                                                                        \
    CL(0, a01, a11, b01, b11);                                               \
    if (do_next) {                                                           \
      pA2 = *(const v4i*)(asl[sn] + 2048);                                   \
      pA3 = *(const v4i*)(asl[sn] + 3072);                                   \
    }                                                                        \
    CL(2, a21, a31, b01, b11);                                               \
    if (do_next) {                                                           \
      UNPK(a00, a01, pA0);                                                   \
      UNPK(a10, a11, pA1);                                                   \
      UNPK(b00, b01, pB0);                                                   \
      UNPK(b10, b11, pB1);                                                   \
    }                                                                        \
  } while (0)

  // prologue: stage tiles 0,1,2; certify slot 0; read+unpack slot-0 operands.
  // After the three stages aS/bS point at tile 3 = first in-loop stage target.
  gll16(aS, dal[0]); gll16(bS, dbl[0]); aS += 8192; bS += 8192;
  gll16(aS, dal[1]); gll16(bS, dbl[1]); aS += 8192; bS += 8192;
  gll16(aS, dal[2]); gll16(bS, dbl[2]); aS += 8192; bS += 8192;
  asm volatile("s_waitcnt vmcnt(4)" ::: "memory");
  __builtin_amdgcn_s_barrier();
  __builtin_amdgcn_sched_barrier(0);
  pA0 = *(const v4i*)(asl[0]);
  pA1 = *(const v4i*)(asl[0] + 1024);
  pA2 = *(const v4i*)(asl[0] + 2048);
  pA3 = *(const v4i*)(asl[0] + 3072);
  pB0 = *(const v4i*)(bsl[0]);
  pB1 = *(const v4i*)(bsl[0] + 1024);
  UNPK(a00, a01, pA0);
  UNPK(a10, a11, pA1);
  UNPK(b00, b01, pB0);
  UNPK(b10, b11, pB1);

  // K-loop: kt = 0..59 in groups of 4 (literal slots), then 60..63 tail.
  for (int g = 0; g < 15; ++g) {
    TILE(0, 1, 3, 1, 1, 2);
    TILE(1, 2, 0, 1, 1, 2);
    TILE(2, 3, 1, 1, 1, 2);
    TILE(3, 0, 2, 1, 1, 2);
  }
  TILE(0, 1, 3, 1, 1, 2);   // kt=60, stages slot 3 (tile 63, last)
  TILE(1, 2, 0, 0, 1, 2);   // kt=61
  TILE(2, 3, 0, 0, 1, 0);   // kt=62
  TILE(3, 0, 0, 0, 0, -1);  // kt=63, pure drain

#undef TILE
#undef CL
#undef UNPK

  // epilogue: C/D 32x32: col = lane&31, row = (reg&3)+8*(reg>>2)+4*(lane>>5)
  const int colb = bx * 256 + wn * 64 + (lane & 31);
  int sw0 = sw[colb];
  int sw1 = sw[colb + 32];
  float wv0 = wsc[colb];
  float wv1 = wsc[colb + 32];
  const int rw = by * 256 + wm * 128 + ((lane >> 5) << 2);
#pragma unroll
  for (int rb = 0; rb < 4; ++rb) {
#pragma unroll
    for (int g = 0; g < 4; ++g) {
#pragma unroll
      for (int j = 0; j < 4; ++j) {
        int r = rw + rb * 32 + g * 8 + j;
        int reg = g * 4 + j;
        int sv = sa[r];
        float s = xs[r];
        float* orow = out + (size_t)r * 4096 + colb;
        orow[0]  = (float)(acc[rb][0][reg] - 8 * (sv + sw0)) * (s * wv0);
        orow[32] = (float)(acc[rb][1][reg] - 8 * (sv + sw1)) * (s * wv1);
      }
    }
  }
}

extern "C" void kernel_launch(void* const* d_in, const int* in_sizes, int n_in,
                              void* d_out, int out_size, void* d_ws, size_t ws_size,
                              hipStream_t stream) {
  const float* x = (const float*)d_in[0];
  const int* wp = (const int*)d_in[1];
  const float* wsc = (const float*)d_in[2];
  float* out = (float*)d_out;
  char* ws = (char*)d_ws;

  char* xq = ws;                                   // packed 8192*2048 = 16777216 B
  char* wq = ws + 16777216;                        // packed 4096*2048 =  8388608 B
  float* xs = (float*)(ws + 25165824);             // 8192*4
  int* sa = (int*)(ws + 25165824 + 32768);         // 8192*4
  int* sw = (int*)(ws + 25165824 + 65536);         // 4096*4

  hipLaunchKernelGGL(unpack_w, dim3(64, 16), dim3(256), 0, stream, wp, wq);
  hipLaunchKernelGGL(sum_w, dim3(4096), dim3(256), 0, stream, wp, sw);
  hipLaunchKernelGGL(quant_x, dim3(2048), dim3(256), 0, stream, x, xq, xs, sa);
  hipLaunchKernelGGL(gemm_i8, dim3(512), dim3(512), 0, stream, xq, wq, xs, sa, sw, wsc, out);
}

// Round 15
// 873.405 us; speedup vs baseline: 1.0554x; 1.0554x over previous
//
#include <hip/hip_runtime.h>

#define SCALE_EPS 1e-5f

typedef int v4i __attribute__((ext_vector_type(4)));
typedef int v16i __attribute__((ext_vector_type(16)));

static __device__ __forceinline__ void gll16(const void* g, void* l) {
  __builtin_amdgcn_global_load_lds(
      (const __attribute__((address_space(1))) unsigned int*)g,
      (__attribute__((address_space(3))) unsigned int*)l,
      16, 0, 0);
}

// Nibble-pair packed operand format (both A and B), biased u = q+8:
//   packed byte e of a 32x32 k-pair fragment: u[k] | u[k+32]<<4
//   fragment lane l = kh*32 + (row_or_col % 32); ds_read_b128 yields BOTH
//   ks=0 (lo nibbles) and ks=1 (hi nibbles) v4i MFMA operands.
// A tile (256 rows x 64 k, packed 8 KiB) at xq + (mt*64+kc)*8192
// B tile (256 cols x 64 k, packed 8 KiB) at wq + (nt*64+kc)*8192
// Bias removal: C = raw - 8*(sa_signed[t] + swU_biased[o])  (exact).

// ---------------------------------------------------------------------------
// Weight unpack: packed int32 [4096][2048] -> biased nibble-pair tiles.
// ---------------------------------------------------------------------------
__global__ __launch_bounds__(256) void unpack_w(const int* __restrict__ wp,
                                                char* __restrict__ wq) {
  const int kc = blockIdx.x;   // 0..63
  const int nt2 = blockIdx.y;  // 0..15 (256-col tiles)
  const int tid = threadIdx.x;
  char* tile = wq + ((size_t)nt2 * 64 + kc) * 8192;
#pragma unroll
  for (int it = 0; it < 8; ++it) {
    int idx = it * 256 + tid;      // 0..2047
    int c = idx >> 3;              // col in tile 0..255
    int rem = idx & 7;
    int kh = rem >> 2, q = rem & 3;
    const int* src = wp + (size_t)(nt2 * 256 + c) * 2048 + kc * 32 + kh * 8 + q * 2;
    int i0 = src[0], i1 = src[1], j0 = src[16], j1 = src[17];
    unsigned dw = ((unsigned)i0 & 15) | (((unsigned)j0 & 15) << 4) |
                  ((((unsigned)i0 >> 4) & 15) << 8) | ((((unsigned)j0 >> 4) & 15) << 12) |
                  (((unsigned)i1 & 15) << 16) | (((unsigned)j1 & 15) << 20) |
                  ((((unsigned)i1 >> 4) & 15) << 24) | ((((unsigned)j1 >> 4) & 15) << 28);
    dw ^= 0x88888888u;  // raw nibble v -> v^8 = q+8 (biased)
    *(unsigned*)(tile + (c >> 5) * 1024 + (kh * 32 + (c & 31)) * 16 + q * 4) = dw;
  }
}

// ---------------------------------------------------------------------------
// Per-out-feature BIASED nibble sum: swU[o] = sum_k (q_w + 8).
// ---------------------------------------------------------------------------
__global__ __launch_bounds__(256) void sum_w(const int* __restrict__ wp,
                                             int* __restrict__ sw) {
  __shared__ int ls[4];
  const int row = blockIdx.x;
  const int tid = threadIdx.x;
  const v4i* src = (const v4i*)(wp + (size_t)row * 2048 + tid * 8);
  v4i m0 = src[0], m1 = src[1];
  int s = 0;
#pragma unroll
  for (int j = 0; j < 4; ++j) {
    int a = (j == 0) ? m0.x : (j == 1) ? m0.y : (j == 2) ? m0.z : m0.w;
    int b = (j == 0) ? m1.x : (j == 1) ? m1.y : (j == 2) ? m1.z : m1.w;
    s += ((a & 15) ^ 8) + (((a >> 4) & 15) ^ 8) + ((b & 15) ^ 8) + (((b >> 4) & 15) ^ 8);
  }
#pragma unroll
  for (int d = 1; d < 64; d <<= 1) s += __shfl_xor(s, d, 64);
  if ((tid & 63) == 0) ls[tid >> 6] = s;
  __syncthreads();
  if (tid == 0) sw[row] = ls[0] + ls[1] + ls[2] + ls[3];
}

// ---------------------------------------------------------------------------
// Activation quant: per-row absmax scale, q = clip(rint(x/scale),-8,7),
// nibble-pair packed tiles (u = q+8) + per-token SIGNED sum sa[t].
// ---------------------------------------------------------------------------
__global__ __launch_bounds__(256) void quant_x(const float* __restrict__ x,
                                               char* __restrict__ xq,
                                               float* __restrict__ xs,
                                               int* __restrict__ sa) {
  __shared__ float lmax[4][4];
  __shared__ int lsum[4][4];
  const int tid = threadIdx.x;
  const int w = tid >> 6;        // wave -> 16 kc chunk
  const int l = tid & 63;
  const int t0 = blockIdx.x * 4;
  const int row = l >> 4;
  const int t = t0 + row;
  const int sub = l & 15;
  const int kcl = sub >> 3;      // which of 2 kc per s
  const int kh = (sub >> 2) & 1;
  const int j = sub & 3;

  float4 va[8], vb[8];
  float m = 0.0f;
#pragma unroll
  for (int s = 0; s < 8; ++s) {
    int kc = w * 16 + s * 2 + kcl;
    const float* p = x + (size_t)t * 4096 + kc * 64 + kh * 16 + j * 4;
    va[s] = *(const float4*)(p);
    vb[s] = *(const float4*)(p + 32);
    m = fmaxf(m, fmaxf(fmaxf(fabsf(va[s].x), fabsf(va[s].y)),
                       fmaxf(fabsf(va[s].z), fabsf(va[s].w))));
    m = fmaxf(m, fmaxf(fmaxf(fabsf(vb[s].x), fabsf(vb[s].y)),
                       fmaxf(fabsf(vb[s].z), fabsf(vb[s].w))));
  }
#pragma unroll
  for (int d = 1; d < 16; d <<= 1) m = fmaxf(m, __shfl_xor(m, d, 64));
  if (sub == 0) lmax[w][row] = m;
  __syncthreads();
  float rm = fmaxf(fmaxf(lmax[0][row], lmax[1][row]),
                   fmaxf(lmax[2][row], lmax[3][row]));
  float scale = fmaxf(rm / 7.0f, SCALE_EPS);
  if (w == 0 && sub == 0) xs[t] = scale;

  char* dst0 = xq + (size_t)(t >> 8) * 524288 + ((t & 255) >> 5) * 1024 +
               (kh * 32 + (t & 31)) * 16 + j * 4;

  int isum = 0;
#pragma unroll
  for (int s = 0; s < 8; ++s) {
    int kc = w * 16 + s * 2 + kcl;
    int q0 = (int)fminf(fmaxf(rintf(va[s].x / scale), -8.0f), 7.0f);
    int q1 = (int)fminf(fmaxf(rintf(va[s].y / scale), -8.0f), 7.0f);
    int q2 = (int)fminf(fmaxf(rintf(va[s].z / scale), -8.0f), 7.0f);
    int q3 = (int)fminf(fmaxf(rintf(va[s].w / scale), -8.0f), 7.0f);
    int q4 = (int)fminf(fmaxf(rintf(vb[s].x / scale), -8.0f), 7.0f);
    int q5 = (int)fminf(fmaxf(rintf(vb[s].y / scale), -8.0f), 7.0f);
    int q6 = (int)fminf(fmaxf(rintf(vb[s].z / scale), -8.0f), 7.0f);
    int q7 = (int)fminf(fmaxf(rintf(vb[s].w / scale), -8.0f), 7.0f);
    isum += q0 + q1 + q2 + q3 + q4 + q5 + q6 + q7;
    unsigned dw = (unsigned)((q0 + 8) | ((q4 + 8) << 4)) |
                  ((unsigned)((q1 + 8) | ((q5 + 8) << 4)) << 8) |
                  ((unsigned)((q2 + 8) | ((q6 + 8) << 4)) << 16) |
                  ((unsigned)((q3 + 8) | ((q7 + 8) << 4)) << 24);
    *(unsigned*)(dst0 + (size_t)kc * 8192) = dw;
  }
#pragma unroll
  for (int dd = 1; dd < 16; dd <<= 1) isum += __shfl_xor(isum, dd, 64);
  if (sub == 0) lsum[w][row] = isum;
  __syncthreads();
  if (w == 0 && sub == 0)
    sa[t] = lsum[0][row] + lsum[1][row] + lsum[2][row] + lsum[3][row];
}

// ---------------------------------------------------------------------------
// Packed-nibble GEMM, 256x256 tile, 8 waves (2Mx4N), BK=64, mfma 32x32x32 i8.
// R14 = R13 without the spill: the hoisted pointer ARRAYS (asl/bsl/dal/dbl,
// 32 VGPRs of generic 64-bit pointers) pushed the unified budget to exactly
// 256 and the allocator spilled (WRITE 2.8 GB scratch). Replaced by LITERAL
// slot expressions: lds[SN] + base is a compile-time LDS address; with the
// K-loop unrolled x4 every ds_read folds to ONE CSE'd base register +
// 16-bit offset immediate (max 61440 < 65536). Zero live pointers, zero
// per-tile address VALU. Stage srcs stay incremental (aS/bS += 8192).
// Schedule = R8's proven skeleton: mid-tile counted vmcnt(2)+barrier,
// packed-pair rotation, splat-vector unpack, setprio.
// Epilogue: C = raw - 8*(sa + swU)  (exact).
// ---------------------------------------------------------------------------
__global__ __launch_bounds__(512, 2) void gemm_i8(const char* __restrict__ xq,
                                                  const char* __restrict__ wq,
                                                  const float* __restrict__ xs,
                                                  const int* __restrict__ sa,
                                                  const int* __restrict__ sw,
                                                  const float* __restrict__ wsc,
                                                  float* __restrict__ out) {
  __shared__ char lds[4][16384];
  const int tid = threadIdx.x;
  const int wid = tid >> 6;
  const int lane = tid & 63;
  const int wm = wid >> 2;         // 0..1 : M half (128 rows)
  const int wn = wid & 3;          // 0..3 : N quarter (64 cols)

  const int bid = blockIdx.x;
  const int wg = (bid & 7) * 64 + (bid >> 3);
  const int by = wg >> 4;          // 0..31
  const int bx = wg & 15;          // 0..15

  const int toff = tid * 16;       // 0..8191
  const int aro = wm * 4096 + lane * 16;          // A-read base offset
  const int bro = 8192 + wn * 2048 + lane * 16;   // B-read base offset

  const char* aS = xq + (size_t)by * 524288 + toff;  // stage src, tile 0
  const char* bS = wq + (size_t)bx * 524288 + toff;

  v16i acc[4][2] = {};             // acc[rb][nf]
  v4i pA0, pA1, pA2, pA3, pB0, pB1;                  // packed (next tile)
  v4i a00, a01, a10, a11, a20, a21, a30, a31;        // unpacked A [rb][ks]
  v4i b00, b01, b10, b11;                            // unpacked B [nf][ks]
  const v4i M4 = (v4i)(0x0f0f0f0f);

#define UNPK(d0, d1, p)                            \
  do {                                             \
    d0 = (p) & M4;                                 \
    d1 = ((p) >> 4) & M4;                          \
  } while (0)

  // 4 mfma: rows {rb, rb+1} x col-frags {0,1}
#define CL(rb, xx, yy, bA, bB)                                                 \
  do {                                                                         \
    __builtin_amdgcn_s_setprio(1);                                             \
    acc[rb][0] = __builtin_amdgcn_mfma_i32_32x32x32_i8(xx, bA, acc[rb][0], 0, 0, 0);   \
    acc[rb][1] = __builtin_amdgcn_mfma_i32_32x32x32_i8(xx, bB, acc[rb][1], 0, 0, 0);   \
    acc[rb + 1][0] = __builtin_amdgcn_mfma_i32_32x32x32_i8(yy, bA, acc[rb + 1][0], 0, 0, 0); \
    acc[rb + 1][1] = __builtin_amdgcn_mfma_i32_32x32x32_i8(yy, bB, acc[rb + 1][1], 0, 0, 0); \
    __builtin_amdgcn_s_setprio(0);                                             \
  } while (0)

  // One K-tile. sn / ss are LITERAL slot numbers after unrolling, so every
  // LDS address below is (CSE'd base reg) + compile-time immediate.
#define TILE(sn, ss, do_stage, do_next, vm)                                  \
  do {                                                                       \
    /* first half: unpack rb2,rb3 (held from prev tile); ks0 MFMAs */        \
    UNPK(a20, a21, pA2);                                                     \
    UNPK(a30, a31, pA3);                                                     \
    CL(0, a00, a10, b00, b10);                                               \
    CL(2, a20, a30, b00, b10);                                               \
    /* mid-tile: certify slot sn's DMA (counted), sync */                    \
    if ((vm) == 2) asm volatile("s_waitcnt vmcnt(2)" ::: "memory");          \
    else if ((vm) == 0) asm volatile("s_waitcnt vmcnt(0)" ::: "memory");     \
    __builtin_amdgcn_s_barrier();                                            \
    __builtin_amdgcn_sched_barrier(0);                                       \
    /* second half: stage slot ss; read slot sn packed; ks1 MFMAs; unpack */ \
    if (do_stage) {                                                          \
      gll16(aS, lds[ss] + toff);                                             \
      gll16(bS, lds[ss] + 8192 + toff);                                      \
      aS += 8192; bS += 8192;                                                \
    }                                                                        \
    if (do_next) {                                                           \
      pA0 = *(const v4i*)(lds[sn] + aro);                                    \
      pA1 = *(const v4i*)(lds[sn] + aro + 1024);                             \
      pB0 = *(const v4i*)(lds[sn] + bro);                                    \
      pB1 = *(const v4i*)(lds[sn] + bro + 1024);                             \
    }                                                                        \
    CL(0, a01, a11, b01, b11);                                               \
    if (do_next) {                                                           \
      pA2 = *(const v4i*)(lds[sn] + aro + 2048);                             \
      pA3 = *(const v4i*)(lds[sn] + aro + 3072);                             \
    }                                                                        \
    CL(2, a21, a31, b01, b11);                                               \
    if (do_next) {                                                           \
      UNPK(a00, a01, pA0);                                                   \
      UNPK(a10, a11, pA1);                                                   \
      UNPK(b00, b01, pB0);                                                   \
      UNPK(b10, b11, pB1);                                                   \
    }                                                                        \
  } while (0)

  // prologue: stage tiles 0,1,2; certify slot 0; read+unpack slot-0 operands.
  // After the three stages aS/bS point at tile 3 = first in-loop stage target.
  gll16(aS, lds[0] + toff); gll16(bS, lds[0] + 8192 + toff); aS += 8192; bS += 8192;
  gll16(aS, lds[1] + toff); gll16(bS, lds[1] + 8192 + toff); aS += 8192; bS += 8192;
  gll16(aS, lds[2] + toff); gll16(bS, lds[2] + 8192 + toff); aS += 8192; bS += 8192;
  asm volatile("s_waitcnt vmcnt(4)" ::: "memory");
  __builtin_amdgcn_s_barrier();
  __builtin_amdgcn_sched_barrier(0);
  pA0 = *(const v4i*)(lds[0] + aro);
  pA1 = *(const v4i*)(lds[0] + aro + 1024);
  pA2 = *(const v4i*)(lds[0] + aro + 2048);
  pA3 = *(const v4i*)(lds[0] + aro + 3072);
  pB0 = *(const v4i*)(lds[0] + bro);
  pB1 = *(const v4i*)(lds[0] + bro + 1024);
  UNPK(a00, a01, pA0);
  UNPK(a10, a11, pA1);
  UNPK(b00, b01, pB0);
  UNPK(b10, b11, pB1);

  // K-loop: kt = 0..59 in groups of 4 (literal slots), then 60..63 tail.
  // TILE at kt uses sn=(kt+1)&3, ss=(kt+3)&3.
  for (int g = 0; g < 15; ++g) {
    TILE(1, 3, 1, 1, 2);   // kt = 4g+0
    TILE(2, 0, 1, 1, 2);   // kt = 4g+1
    TILE(3, 1, 1, 1, 2);   // kt = 4g+2
    TILE(0, 2, 1, 1, 2);   // kt = 4g+3
  }
  TILE(1, 3, 1, 1, 2);     // kt=60, stages slot 3 (tile 63, last)
  TILE(2, 0, 0, 1, 2);     // kt=61
  TILE(3, 0, 0, 1, 0);     // kt=62
  TILE(0, 0, 0, 0, -1);    // kt=63, pure drain

#undef TILE
#undef CL
#undef UNPK

  // epilogue: C/D 32x32: col = lane&31, row = (reg&3)+8*(reg>>2)+4*(lane>>5)
  const int colb = bx * 256 + wn * 64 + (lane & 31);
  int sw0 = sw[colb];
  int sw1 = sw[colb + 32];
  float wv0 = wsc[colb];
  float wv1 = wsc[colb + 32];
  const int rw = by * 256 + wm * 128 + ((lane >> 5) << 2);
#pragma unroll
  for (int rb = 0; rb < 4; ++rb) {
#pragma unroll
    for (int g = 0; g < 4; ++g) {
#pragma unroll
      for (int j = 0; j < 4; ++j) {
        int r = rw + rb * 32 + g * 8 + j;
        int reg = g * 4 + j;
        int sv = sa[r];
        float s = xs[r];
        float* orow = out + (size_t)r * 4096 + colb;
        orow[0]  = (float)(acc[rb][0][reg] - 8 * (sv + sw0)) * (s * wv0);
        orow[32] = (float)(acc[rb][1][reg] - 8 * (sv + sw1)) * (s * wv1);
      }
    }
  }
}

extern "C" void kernel_launch(void* const* d_in, const int* in_sizes, int n_in,
                              void* d_out, int out_size, void* d_ws, size_t ws_size,
                              hipStream_t stream) {
  const float* x = (const float*)d_in[0];
  const int* wp = (const int*)d_in[1];
  const float* wsc = (const float*)d_in[2];
  float* out = (float*)d_out;
  char* ws = (char*)d_ws;

  char* xq = ws;                                   // packed 8192*2048 = 16777216 B
  char* wq = ws + 16777216;                        // packed 4096*2048 =  8388608 B
  float* xs = (float*)(ws + 25165824);             // 8192*4
  int* sa = (int*)(ws + 25165824 + 32768);         // 8192*4
  int* sw = (int*)(ws + 25165824 + 65536);         // 4096*4

  hipLaunchKernelGGL(unpack_w, dim3(64, 16), dim3(256), 0, stream, wp, wq);
  hipLaunchKernelGGL(sum_w, dim3(4096), dim3(256), 0, stream, wp, sw);
  hipLaunchKernelGGL(quant_x, dim3(2048), dim3(256), 0, stream, x, xq, xs, sa);
  hipLaunchKernelGGL(gemm_i8, dim3(512), dim3(512), 0, stream, xq, wq, xs, sa, sw, wsc, out);
}

// Round 16
// 164.502 us; speedup vs baseline: 5.6037x; 5.3094x over previous
//
#include <hip/hip_runtime.h>

#define SCALE_EPS 1e-5f

typedef int v4i __attribute__((ext_vector_type(4)));
typedef int v16i __attribute__((ext_vector_type(16)));

static __device__ __forceinline__ void gll16(const void* g, void* l) {
  __builtin_amdgcn_global_load_lds(
      (const __attribute__((address_space(1))) unsigned int*)g,
      (__attribute__((address_space(3))) unsigned int*)l,
      16, 0, 0);
}

// Nibble-pair packed operand format (both A and B), biased u = q+8:
//   packed byte e of a 32x32 k-pair fragment: u[k] | u[k+32]<<4
//   fragment lane l = kh*32 + (row_or_col % 32); ds_read_b128 yields BOTH
//   ks=0 (lo nibbles) and ks=1 (hi nibbles) v4i MFMA operands.
// A tile (256 rows x 64 k, packed 8 KiB) at xq + (mt*64+kc)*8192
// B tile (256 cols x 64 k, packed 8 KiB) at wq + (nt*64+kc)*8192
// Bias removal: C = raw - 8*(sa_signed[t] + swU_biased[o])  (exact).
//
// R15 = exact revert to the R8 GEMM (best measured: 164.06 us total,
// gemm 114.2 us, no spill). R9-R14 post-mortems: every scheduling-freedom
// addition (sched_barrier pinning, occupancy forcing, 4x unroll, pointer
// arrays) converted to register spill (acc=128 AGPR leaves ~100 VGPR slack
// at the 256-unified budget) or hit the VALU wall (R11). The rolled 2-TILE
// loop with runtime slots is what keeps peak pressure at ~228 regs.
// ---------------------------------------------------------------------------
__global__ __launch_bounds__(256) void unpack_w(const int* __restrict__ wp,
                                                char* __restrict__ wq) {
  const int kc = blockIdx.x;   // 0..63
  const int nt2 = blockIdx.y;  // 0..15 (256-col tiles)
  const int tid = threadIdx.x;
  char* tile = wq + ((size_t)nt2 * 64 + kc) * 8192;
#pragma unroll
  for (int it = 0; it < 8; ++it) {
    int idx = it * 256 + tid;      // 0..2047
    int c = idx >> 3;              // col in tile 0..255
    int rem = idx & 7;
    int kh = rem >> 2, q = rem & 3;
    const int* src = wp + (size_t)(nt2 * 256 + c) * 2048 + kc * 32 + kh * 8 + q * 2;
    int i0 = src[0], i1 = src[1], j0 = src[16], j1 = src[17];
    unsigned dw = ((unsigned)i0 & 15) | (((unsigned)j0 & 15) << 4) |
                  ((((unsigned)i0 >> 4) & 15) << 8) | ((((unsigned)j0 >> 4) & 15) << 12) |
                  (((unsigned)i1 & 15) << 16) | (((unsigned)j1 & 15) << 20) |
                  ((((unsigned)i1 >> 4) & 15) << 24) | ((((unsigned)j1 >> 4) & 15) << 28);
    dw ^= 0x88888888u;  // raw nibble v -> v^8 = q+8 (biased)
    *(unsigned*)(tile + (c >> 5) * 1024 + (kh * 32 + (c & 31)) * 16 + q * 4) = dw;
  }
}

// ---------------------------------------------------------------------------
// Per-out-feature BIASED nibble sum: swU[o] = sum_k (q_w + 8).
// ---------------------------------------------------------------------------
__global__ __launch_bounds__(256) void sum_w(const int* __restrict__ wp,
                                             int* __restrict__ sw) {
  __shared__ int ls[4];
  const int row = blockIdx.x;
  const int tid = threadIdx.x;
  const v4i* src = (const v4i*)(wp + (size_t)row * 2048 + tid * 8);
  v4i m0 = src[0], m1 = src[1];
  int s = 0;
#pragma unroll
  for (int j = 0; j < 4; ++j) {
    int a = (j == 0) ? m0.x : (j == 1) ? m0.y : (j == 2) ? m0.z : m0.w;
    int b = (j == 0) ? m1.x : (j == 1) ? m1.y : (j == 2) ? m1.z : m1.w;
    s += ((a & 15) ^ 8) + (((a >> 4) & 15) ^ 8) + ((b & 15) ^ 8) + (((b >> 4) & 15) ^ 8);
  }
#pragma unroll
  for (int d = 1; d < 64; d <<= 1) s += __shfl_xor(s, d, 64);
  if ((tid & 63) == 0) ls[tid >> 6] = s;
  __syncthreads();
  if (tid == 0) sw[row] = ls[0] + ls[1] + ls[2] + ls[3];
}

// ---------------------------------------------------------------------------
// Activation quant: per-row absmax scale, q = clip(rint(x/scale),-8,7),
// nibble-pair packed tiles (u = q+8) + per-token SIGNED sum sa[t].
// ---------------------------------------------------------------------------
__global__ __launch_bounds__(256) void quant_x(const float* __restrict__ x,
                                               char* __restrict__ xq,
                                               float* __restrict__ xs,
                                               int* __restrict__ sa) {
  __shared__ float lmax[4][4];
  __shared__ int lsum[4][4];
  const int tid = threadIdx.x;
  const int w = tid >> 6;        // wave -> 16 kc chunk
  const int l = tid & 63;
  const int t0 = blockIdx.x * 4;
  const int row = l >> 4;
  const int t = t0 + row;
  const int sub = l & 15;
  const int kcl = sub >> 3;      // which of 2 kc per s
  const int kh = (sub >> 2) & 1;
  const int j = sub & 3;

  float4 va[8], vb[8];
  float m = 0.0f;
#pragma unroll
  for (int s = 0; s < 8; ++s) {
    int kc = w * 16 + s * 2 + kcl;
    const float* p = x + (size_t)t * 4096 + kc * 64 + kh * 16 + j * 4;
    va[s] = *(const float4*)(p);
    vb[s] = *(const float4*)(p + 32);
    m = fmaxf(m, fmaxf(fmaxf(fabsf(va[s].x), fabsf(va[s].y)),
                       fmaxf(fabsf(va[s].z), fabsf(va[s].w))));
    m = fmaxf(m, fmaxf(fmaxf(fabsf(vb[s].x), fabsf(vb[s].y)),
                       fmaxf(fabsf(vb[s].z), fabsf(vb[s].w))));
  }
#pragma unroll
  for (int d = 1; d < 16; d <<= 1) m = fmaxf(m, __shfl_xor(m, d, 64));
  if (sub == 0) lmax[w][row] = m;
  __syncthreads();
  float rm = fmaxf(fmaxf(lmax[0][row], lmax[1][row]),
                   fmaxf(lmax[2][row], lmax[3][row]));
  float scale = fmaxf(rm / 7.0f, SCALE_EPS);
  if (w == 0 && sub == 0) xs[t] = scale;

  char* dst0 = xq + (size_t)(t >> 8) * 524288 + ((t & 255) >> 5) * 1024 +
               (kh * 32 + (t & 31)) * 16 + j * 4;

  int isum = 0;
#pragma unroll
  for (int s = 0; s < 8; ++s) {
    int kc = w * 16 + s * 2 + kcl;
    int q0 = (int)fminf(fmaxf(rintf(va[s].x / scale), -8.0f), 7.0f);
    int q1 = (int)fminf(fmaxf(rintf(va[s].y / scale), -8.0f), 7.0f);
    int q2 = (int)fminf(fmaxf(rintf(va[s].z / scale), -8.0f), 7.0f);
    int q3 = (int)fminf(fmaxf(rintf(va[s].w / scale), -8.0f), 7.0f);
    int q4 = (int)fminf(fmaxf(rintf(vb[s].x / scale), -8.0f), 7.0f);
    int q5 = (int)fminf(fmaxf(rintf(vb[s].y / scale), -8.0f), 7.0f);
    int q6 = (int)fminf(fmaxf(rintf(vb[s].z / scale), -8.0f), 7.0f);
    int q7 = (int)fminf(fmaxf(rintf(vb[s].w / scale), -8.0f), 7.0f);
    isum += q0 + q1 + q2 + q3 + q4 + q5 + q6 + q7;
    unsigned dw = (unsigned)((q0 + 8) | ((q4 + 8) << 4)) |
                  ((unsigned)((q1 + 8) | ((q5 + 8) << 4)) << 8) |
                  ((unsigned)((q2 + 8) | ((q6 + 8) << 4)) << 16) |
                  ((unsigned)((q3 + 8) | ((q7 + 8) << 4)) << 24);
    *(unsigned*)(dst0 + (size_t)kc * 8192) = dw;
  }
#pragma unroll
  for (int dd = 1; dd < 16; dd <<= 1) isum += __shfl_xor(isum, dd, 64);
  if (sub == 0) lsum[w][row] = isum;
  __syncthreads();
  if (w == 0 && sub == 0)
    sa[t] = lsum[0][row] + lsum[1][row] + lsum[2][row] + lsum[3][row];
}

// ---------------------------------------------------------------------------
// Packed-nibble GEMM, 256x256 tile, 8 waves (2Mx4N), BK=64, mfma 32x32x32 i8.
// EXACT R8 structure: rolled 2-TILE loop, runtime slot indices, mid-tile
// counted vmcnt(2)+barrier, packed-pair register rotation, splat-vector
// unpack, setprio. Measured: 114.2 us, MfmaUtil 52.9, VALUBusy 47.4, no
// spill (VGPR 100 + 128 AGPR = 228 < 256 budget).
// ---------------------------------------------------------------------------
__global__ __launch_bounds__(512, 2) void gemm_i8(const char* __restrict__ xq,
                                                  const char* __restrict__ wq,
                                                  const float* __restrict__ xs,
                                                  const int* __restrict__ sa,
                                                  const int* __restrict__ sw,
                                                  const float* __restrict__ wsc,
                                                  float* __restrict__ out) {
  __shared__ char lds[4][16384];
  const int tid = threadIdx.x;
  const int wid = tid >> 6;
  const int lane = tid & 63;
  const int wm = wid >> 2;         // 0..1 : M half (128 rows)
  const int wn = wid & 3;          // 0..3 : N quarter (64 cols)

  const int bid = blockIdx.x;
  const int wg = (bid & 7) * 64 + (bid >> 3);
  const int by = wg >> 4;          // 0..31
  const int bx = wg & 15;          // 0..15

  const int toff = tid * 16;       // 0..8191
  const char* aSrc = xq + (size_t)by * 524288;
  const char* bSrc = wq + (size_t)bx * 524288;
  const int laoff = lane * 16;

  v16i acc[4][2] = {};             // acc[rb][nf]
  v4i pA0, pA1, pA2, pA3, pB0, pB1;                    // packed (next/current)
  v4i a00, a01, a10, a11, a20, a21, a30, a31;          // unpacked A [rb][ks]
  v4i b00, b01, b10, b11;                              // unpacked B [nf][ks]
  const unsigned MSK = 0x0f0f0f0fu;

#define LO4(w) (int)((unsigned)(w) & MSK)
#define HI4(w) (int)(((unsigned)(w) >> 4) & MSK)
#define UNPK(d0, d1, p)                                        \
  do {                                                         \
    d0 = (v4i){LO4((p).x), LO4((p).y), LO4((p).z), LO4((p).w)}; \
    d1 = (v4i){HI4((p).x), HI4((p).y), HI4((p).z), HI4((p).w)}; \
  } while (0)

#define STAGE2(kt)                                             \
  do {                                                         \
    char* d_ = lds[(kt) & 3] + toff;                           \
    gll16(aSrc + (size_t)(kt) * 8192 + toff, d_);              \
    gll16(bSrc + (size_t)(kt) * 8192 + toff, d_ + 8192);       \
  } while (0)

  // 4 mfma: rows {rb, rb+1} x col-frags {0,1}
#define CL(rb, xx, yy, bA, bB)                                                 \
  do {                                                                         \
    __builtin_amdgcn_s_setprio(1);                                             \
    acc[rb][0] = __builtin_amdgcn_mfma_i32_32x32x32_i8(xx, bA, acc[rb][0], 0, 0, 0);   \
    acc[rb][1] = __builtin_amdgcn_mfma_i32_32x32x32_i8(xx, bB, acc[rb][1], 0, 0, 0);   \
    acc[rb + 1][0] = __builtin_amdgcn_mfma_i32_32x32x32_i8(yy, bA, acc[rb + 1][0], 0, 0, 0); \
    acc[rb + 1][1] = __builtin_amdgcn_mfma_i32_32x32x32_i8(yy, bB, acc[rb + 1][1], 0, 0, 0); \
    __builtin_amdgcn_s_setprio(0);                                             \
  } while (0)

#define TILE(kt, do_stage, do_next, vm)                                      \
  do {                                                                       \
    const char* An_ = lds[((kt) + 1) & 3] + wm * 4096 + laoff;               \
    const char* Bn_ = lds[((kt) + 1) & 3] + 8192 + wn * 2048 + laoff;        \
    /* first half: unpack rb2,rb3 (packed held from prev tile); ks0 MFMAs */ \
    UNPK(a20, a21, pA2);                                                     \
    UNPK(a30, a31, pA3);                                                     \
    CL(0, a00, a10, b00, b10);                                               \
    CL(2, a20, a30, b00, b10);                                               \
    /* mid-tile: certify slot kt+1 (counted), sync */                        \
    if ((vm) == 2) asm volatile("s_waitcnt vmcnt(2)" ::: "memory");          \
    else if ((vm) == 0) asm volatile("s_waitcnt vmcnt(0)" ::: "memory");     \
    __builtin_amdgcn_s_barrier();                                            \
    __builtin_amdgcn_sched_barrier(0);                                       \
    /* second half: stage kt+3, read kt+1 packed, ks1 MFMAs, unpack next */  \
    if (do_stage) STAGE2((kt) + 3);                                          \
    if (do_next) {                                                           \
      pA0 = *(const v4i*)(An_);                                              \
      pA1 = *(const v4i*)(An_ + 1024);                                       \
      pB0 = *(const v4i*)(Bn_);                                              \
      pB1 = *(const v4i*)(Bn_ + 1024);                                       \
    }                                                                        \
    CL(0, a01, a11, b01, b11);                                               \
    if (do_next) {                                                           \
      pA2 = *(const v4i*)(An_ + 2048);                                       \
      pA3 = *(const v4i*)(An_ + 3072);                                       \
    }                                                                        \
    CL(2, a21, a31, b01, b11);                                               \
    if (do_next) {                                                           \
      UNPK(a00, a01, pA0);                                                   \
      UNPK(a10, a11, pA1);                                                   \
      UNPK(b00, b01, pB0);                                                   \
      UNPK(b10, b11, pB1);                                                   \
    }                                                                        \
  } while (0)

  // prologue: stage tiles 0,1,2; certify slot 0; read+unpack slot-0 operands
  STAGE2(0); STAGE2(1); STAGE2(2);
  asm volatile("s_waitcnt vmcnt(4)" ::: "memory");
  __builtin_amdgcn_s_barrier();
  __builtin_amdgcn_sched_barrier(0);
  {
    const char* A0_ = lds[0] + wm * 4096 + laoff;
    const char* B0_ = lds[0] + 8192 + wn * 2048 + laoff;
    pA0 = *(const v4i*)(A0_);
    pA1 = *(const v4i*)(A0_ + 1024);
    pA2 = *(const v4i*)(A0_ + 2048);
    pA3 = *(const v4i*)(A0_ + 3072);
    pB0 = *(const v4i*)(B0_);
    pB1 = *(const v4i*)(B0_ + 1024);
    UNPK(a00, a01, pA0);
    UNPK(a10, a11, pA1);
    UNPK(b00, b01, pB0);
    UNPK(b10, b11, pB1);
  }

  for (int kt = 0; kt < 60; kt += 2) {
    TILE(kt, 1, 1, 2);
    TILE(kt + 1, 1, 1, 2);
  }
  TILE(60, 1, 1, 2);   // stages slot 63 (last)
  TILE(61, 0, 1, 2);
  TILE(62, 0, 1, 0);
  TILE(63, 0, 0, -1);

#undef TILE
#undef CL
#undef STAGE2
#undef UNPK
#undef LO4
#undef HI4

  // epilogue: C/D 32x32: col = lane&31, row = (reg&3)+8*(reg>>2)+4*(lane>>5)
  const int colb = bx * 256 + wn * 64 + (lane & 31);
  int sw0 = sw[colb];
  int sw1 = sw[colb + 32];
  float wv0 = wsc[colb];
  float wv1 = wsc[colb + 32];
  const int rw = by * 256 + wm * 128 + ((lane >> 5) << 2);
#pragma unroll
  for (int rb = 0; rb < 4; ++rb) {
#pragma unroll
    for (int g = 0; g < 4; ++g) {
#pragma unroll
      for (int j = 0; j < 4; ++j) {
        int r = rw + rb * 32 + g * 8 + j;
        int reg = g * 4 + j;
        int sv = sa[r];
        float s = xs[r];
        float* orow = out + (size_t)r * 4096 + colb;
        orow[0]  = (float)(acc[rb][0][reg] - 8 * (sv + sw0)) * (s * wv0);
        orow[32] = (float)(acc[rb][1][reg] - 8 * (sv + sw1)) * (s * wv1);
      }
    }
  }
}

extern "C" void kernel_launch(void* const* d_in, const int* in_sizes, int n_in,
                              void* d_out, int out_size, void* d_ws, size_t ws_size,
                              hipStream_t stream) {
  const float* x = (const float*)d_in[0];
  const int* wp = (const int*)d_in[1];
  const float* wsc = (const float*)d_in[2];
  float* out = (float*)d_out;
  char* ws = (char*)d_ws;

  char* xq = ws;                                   // packed 8192*2048 = 16777216 B
  char* wq = ws + 16777216;                        // packed 4096*2048 =  8388608 B
  float* xs = (float*)(ws + 25165824);             // 8192*4
  int* sa = (int*)(ws + 25165824 + 32768);         // 8192*4
  int* sw = (int*)(ws + 25165824 + 65536);         // 4096*4

  hipLaunchKernelGGL(unpack_w, dim3(64, 16), dim3(256), 0, stream, wp, wq);
  hipLaunchKernelGGL(sum_w, dim3(4096), dim3(256), 0, stream, wp, sw);
  hipLaunchKernelGGL(quant_x, dim3(2048), dim3(256), 0, stream, x, xq, xs, sa);
  hipLaunchKernelGGL(gemm_i8, dim3(512), dim3(512), 0, stream, xq, wq, xs, sa, sw, wsc, out);
}